// Round 1
// baseline (223.113 us; speedup 1.0000x reference)
//
#include <hip/hip_runtime.h>
#include <stdint.h>

// FourierBlock: B=32, D=64, N=128, L=192, M=32 modes, LH=97.
// 3-kernel plan (all memory-bound, MFMA bf16 compute):
//   K1: q [B,D,N,L] -> X[b,n,i,cat] (cat=2m+c, c=0:cos / 1:-sin), frag-packed bf16 in ws
//   K2: per (n,m) complex GEMM Y[b,o] = X[b,:]·W[:,o], W streamed+LDS-staged, Y bf16 in ws
//   K3: out = basis2 @ Y (iDFT), swizzled LDS transpose for coalesced stores
// ws usage: Xp 33.5MB @ [0), Yp 33.5MB @ [33554432). Requires ws >= 64 MiB.

typedef __attribute__((ext_vector_type(8))) short short8;
typedef __attribute__((ext_vector_type(4))) float f32x4;
typedef __attribute__((ext_vector_type(4))) unsigned short u16x4;

__device__ __forceinline__ unsigned short f2bf(float f) {
  union { float fv; uint32_t u; } v; v.fv = f;
  uint32_t u = v.u;
  u += 0x7fffu + ((u >> 16) & 1u);          // round-to-nearest-even
  return (unsigned short)(u >> 16);
}

__device__ __forceinline__ f32x4 zero4() { f32x4 z; z[0]=0.f; z[1]=0.f; z[2]=0.f; z[3]=0.f; return z; }

#define TWO_PI_OVER_L (6.283185307179586f / 192.0f)

// ---------------------------------------------------------------------------
// K1: DFT.  grid 256 = (n 128, ih 2), 512 thr (8 waves).
// GEMM: rows = flat(i_local*32 + b) 1024 -> 64 Mt(16); cols = cat 64 -> 4 Nt; K = l 192 -> 6 kc(32).
// LDS: phase A: qb [i32][b32][l32] bf16 @0 (65536) + F [cat64] rows 400B @65536 (25600)
//      phase B: X-LDS [cat64][b32][i32] b-stride 72B, cat-stride 2320B (148480 total)
// ---------------------------------------------------------------------------
__global__ __launch_bounds__(512, 2)
void k1_dft(const float* __restrict__ q, unsigned short* __restrict__ Xp) {
  extern __shared__ char smem[];
  const int t = threadIdx.x, lane = t & 63, w = t >> 6;
  const int n = blockIdx.x >> 1, ih = blockIdx.x & 1;

  unsigned short* qb = (unsigned short*)smem;
  char* Fb = smem + 65536;

  // fill DFT basis F[cat][l]: cat=2m+c ; c=0: cos, c=1: -sin  (exact angle via integer mod)
  for (int idx = t; idx < 64 * 192; idx += 512) {
    int cat = idx / 192, l = idx - cat * 192;
    int m = cat >> 1;
    int r = (m * l) % 192;
    float ang = (float)r * TWO_PI_OVER_L;
    float v = (cat & 1) ? -__sinf(ang) : __cosf(ang);
    *(unsigned short*)(Fb + cat * 400 + l * 2) = f2bf(v);
  }

  f32x4 acc[8][4];
#pragma unroll
  for (int a = 0; a < 8; ++a)
#pragma unroll
    for (int bq = 0; bq < 4; ++bq) acc[a][bq] = zero4();

  for (int kc = 0; kc < 6; ++kc) {
    // stage q chunk (32 l) -> bf16 LDS
#pragma unroll
    for (int j = 0; j < 16; ++j) {
      int f = j * 512 + t;
      int lg = f & 7, b = (f >> 3) & 31, il = f >> 8;
      const float4 v = *(const float4*)(q + (((b * 64 + ih * 32 + il) * 128 + n) * 192 + kc * 32 + lg * 4));
      u16x4 h; h[0] = f2bf(v.x); h[1] = f2bf(v.y); h[2] = f2bf(v.z); h[3] = f2bf(v.w);
      *(u16x4*)(qb + (il * 32 + b) * 32 + lg * 4) = h;
    }
    __syncthreads();

    short8 Bf[4];
#pragma unroll
    for (int nt = 0; nt < 4; ++nt) {
      int cat = nt * 16 + (lane & 15);
      Bf[nt] = *(const short8*)(Fb + cat * 400 + (kc * 32 + (lane >> 4) * 8) * 2);
    }
#pragma unroll
    for (int mt = 0; mt < 8; ++mt) {
      int Mt = w * 8 + mt;
      int il = Mt >> 1;
      int b = (Mt & 1) * 16 + (lane & 15);
      short8 A = *(const short8*)((const char*)qb + ((il * 32 + b) * 32 + (lane >> 4) * 8) * 2);
#pragma unroll
      for (int nt = 0; nt < 4; ++nt)
        acc[mt][nt] = __builtin_amdgcn_mfma_f32_16x16x32_bf16(A, Bf[nt], acc[mt][nt], 0, 0, 0);
    }
    __syncthreads();
  }

  // C-frags -> X-LDS transpose ([cat][b][i], b-stride 72 B, cat-stride 2320 B)
#pragma unroll
  for (int mt = 0; mt < 8; ++mt) {
    int Mt = w * 8 + mt;
    int il = Mt >> 1;
    int b0 = (Mt & 1) * 16 + (lane >> 4) * 4;
#pragma unroll
    for (int nt = 0; nt < 4; ++nt) {
      int cat = nt * 16 + (lane & 15);
      char* base = smem + cat * 2320 + il * 2;
      f32x4 v = acc[mt][nt];
#pragma unroll
      for (int r = 0; r < 4; ++r)
        *(unsigned short*)(base + (b0 + r) * 72) = f2bf(v[r]);
    }
  }
  __syncthreads();

  // X-LDS -> Xp global, frag-packed: Xp[n][m][c][kc2][Mt2][lane][e8]
  const int nbase = n * 131072;
#pragma unroll
  for (int j = 0; j < 16; ++j) {
    int f = j * 512 + t;
    int l2 = f & 63, Mt2 = (f >> 6) & 1, c = (f >> 7) & 1, m = f >> 8;
    int cat = 2 * m + c;
    int b = Mt2 * 16 + (l2 & 15);
    int i0 = (l2 >> 4) * 8;
    const char* base = smem + cat * 2320 + b * 72 + i0 * 2;
    u16x4 lo = *(const u16x4*)(base);
    u16x4 hi = *(const u16x4*)(base + 8);
    short8 vv;
    vv[0] = (short)lo[0]; vv[1] = (short)lo[1]; vv[2] = (short)lo[2]; vv[3] = (short)lo[3];
    vv[4] = (short)hi[0]; vv[5] = (short)hi[1]; vv[6] = (short)hi[2]; vv[7] = (short)hi[3];
    int off = nbase + ((((m * 2 + c) * 2 + ih) * 2 + Mt2) * 64 + l2) * 8;
    *(short8*)(Xp + off) = vv;
  }
}

// ---------------------------------------------------------------------------
// K2: per-(n,m) complex channel mix. grid 512 = (n 128, oq 4), 512 thr (8 waves; wave -> 4 m's).
// Y[b32, o16] = X[b,i]·W[i,o] complex, K = i 64 in 2 chunks of 32.
// LDS: W tile [c2][i32][o16][m32] bf16 = 64 KB (single-buffered; 2 blocks/CU hide stalls).
// ---------------------------------------------------------------------------
__global__ __launch_bounds__(512, 4)
void k2_mix(const float* __restrict__ wr, const float* __restrict__ wi,
            const unsigned short* __restrict__ Xp, unsigned short* __restrict__ Yp) {
  extern __shared__ char smem[];
  unsigned short* Wt = (unsigned short*)smem;
  const int t = threadIdx.x, lane = t & 63, w = t >> 6;
  const int n = blockIdx.x >> 2, oq = blockIdx.x & 3;
  const int o_l = lane & 15, ib = (lane >> 4) * 8;

  f32x4 acc[4][2][2];
#pragma unroll
  for (int a = 0; a < 4; ++a)
#pragma unroll
    for (int b2 = 0; b2 < 2; ++b2)
#pragma unroll
      for (int c2 = 0; c2 < 2; ++c2) acc[a][b2][c2] = zero4();

  for (int ic = 0; ic < 2; ++ic) {
    // stage W[n, i-chunk, o-range, all m] both components -> bf16 LDS
#pragma unroll
    for (int j = 0; j < 16; ++j) {
      int f = j * 512 + t;
      int mg = f & 7, o = (f >> 3) & 15, i = (f >> 7) & 31, c = (f >> 12) & 1;
      const float* src = (c ? wi : wr) + ((n * 64 + ic * 32 + i) * 64 + oq * 16 + o) * 32 + mg * 4;
      float4 v = *(const float4*)src;
      u16x4 h; h[0] = f2bf(v.x); h[1] = f2bf(v.y); h[2] = f2bf(v.z); h[3] = f2bf(v.w);
      *(u16x4*)(Wt + ((c * 32 + i) * 16 + o) * 32 + mg * 4) = h;
    }
    __syncthreads();

#pragma unroll
    for (int mm = 0; mm < 4; ++mm) {
      int m = w * 4 + mm;
      // A-frags (X) straight from global, coalesced 1KB per frag
      short8 Ar[2], Ai[2], nAi[2];
#pragma unroll
      for (int Mt = 0; Mt < 2; ++Mt) {
        int ba = ((((n * 32 + m) * 2 + 0) * 2 + ic) * 2 + Mt) * 512 + lane * 8;
        int bb = ((((n * 32 + m) * 2 + 1) * 2 + ic) * 2 + Mt) * 512 + lane * 8;
        Ar[Mt] = *(const short8*)(Xp + ba);
        Ai[Mt] = *(const short8*)(Xp + bb);
#pragma unroll
        for (int e = 0; e < 8; ++e) nAi[Mt][e] = Ai[Mt][e] ^ (short)0x8000;  // -Xi
      }
      // B-frags (W) from LDS (scalar u16 gathers, 2-way banked)
      short8 Br, Bi;
#pragma unroll
      for (int e = 0; e < 8; ++e) {
        Br[e] = (short)Wt[((ib + e) * 16 + o_l) * 32 + m];
        Bi[e] = (short)Wt[((32 + ib + e) * 16 + o_l) * 32 + m];
      }
#pragma unroll
      for (int Mt = 0; Mt < 2; ++Mt) {
        acc[mm][0][Mt] = __builtin_amdgcn_mfma_f32_16x16x32_bf16(Ar[Mt], Br, acc[mm][0][Mt], 0, 0, 0);
        acc[mm][0][Mt] = __builtin_amdgcn_mfma_f32_16x16x32_bf16(nAi[Mt], Bi, acc[mm][0][Mt], 0, 0, 0);
        acc[mm][1][Mt] = __builtin_amdgcn_mfma_f32_16x16x32_bf16(Ar[Mt], Bi, acc[mm][1][Mt], 0, 0, 0);
        acc[mm][1][Mt] = __builtin_amdgcn_mfma_f32_16x16x32_bf16(Ai[Mt], Br, acc[mm][1][Mt], 0, 0, 0);
      }
    }
    __syncthreads();
  }

  // epilogue: Y -> Yp[n][b][cat][o] bf16 (scalar stores, 32B runs)
#pragma unroll
  for (int mm = 0; mm < 4; ++mm) {
    int m = w * 4 + mm;
#pragma unroll
    for (int cc = 0; cc < 2; ++cc) {
      int cat = 2 * m + cc;
#pragma unroll
      for (int Mt = 0; Mt < 2; ++Mt) {
        f32x4 v = acc[mm][cc][Mt];
#pragma unroll
        for (int r = 0; r < 4; ++r) {
          int b = Mt * 16 + (lane >> 4) * 4 + r;
          int idx = ((n * 32 + b) * 64 + cat) * 64 + oq * 16 + o_l;
          Yp[idx] = f2bf(v[r]);
        }
      }
    }
  }
}

// ---------------------------------------------------------------------------
// K3: iDFT + transposed store. grid 4096 = (b 32, n 128), 256 thr (4 waves).
// out[l192, o64] = B2[l, cat64] @ Y[cat, o]; basis in regs via sincos.
// LDS: Ylds [cat64][o64] bf16 (8 KB) + outLDS [o64][l192] fp32 swizzled (48 KB).
// ---------------------------------------------------------------------------
__global__ __launch_bounds__(256, 4)
void k3_idft(const unsigned short* __restrict__ Yp, float* __restrict__ out) {
  extern __shared__ char smem[];
  unsigned short* Yl = (unsigned short*)smem;
  float* ol = (float*)(smem + 8192);
  const int t = threadIdx.x, lane = t & 63, w = t >> 6;
  const int n = blockIdx.x & 127, b = blockIdx.x >> 7;

  // stage Y slice (contiguous 8 KB)
  const unsigned short* ysrc = Yp + (n * 32 + b) * 4096;
#pragma unroll
  for (int j = 0; j < 2; ++j) {
    int f = j * 256 + t;
    *(short8*)(Yl + f * 8) = *(const short8*)(ysrc + f * 8);
  }

  // basis A-frags (regs): wave w -> Mt = w, w+4, w+8
  short8 Af[3][2];
#pragma unroll
  for (int jm = 0; jm < 3; ++jm) {
    int Mt = w + 4 * jm;
    int lt = Mt * 16 + (lane & 15);
#pragma unroll
    for (int kc = 0; kc < 2; ++kc) {
#pragma unroll
      for (int e = 0; e < 8; ++e) {
        int cat = kc * 32 + (lane >> 4) * 8 + e;
        int m = cat >> 1;
        int r = (m * lt) % 192;
        float ang = (float)r * TWO_PI_OVER_L;
        float coef = (m == 0) ? (1.0f / 192.0f) : (2.0f / 192.0f);
        float v = ((cat & 1) ? -__sinf(ang) : __cosf(ang)) * coef;
        Af[jm][kc][e] = (short)f2bf(v);
      }
    }
  }
  __syncthreads();

  f32x4 acc[3][4];
#pragma unroll
  for (int a = 0; a < 3; ++a)
#pragma unroll
    for (int bq = 0; bq < 4; ++bq) acc[a][bq] = zero4();

#pragma unroll
  for (int kc = 0; kc < 2; ++kc) {
    short8 Bf[4];
#pragma unroll
    for (int nt = 0; nt < 4; ++nt)
#pragma unroll
      for (int e = 0; e < 8; ++e) {
        int cat = kc * 32 + (lane >> 4) * 8 + e;
        Bf[nt][e] = (short)Yl[cat * 64 + nt * 16 + (lane & 15)];
      }
#pragma unroll
    for (int jm = 0; jm < 3; ++jm)
#pragma unroll
      for (int nt = 0; nt < 4; ++nt)
        acc[jm][nt] = __builtin_amdgcn_mfma_f32_16x16x32_bf16(Af[jm][kc], Bf[nt], acc[jm][nt], 0, 0, 0);
  }

  // C-frags -> swizzled out-LDS (l ^= (o&7)<<2 breaks the 768B-stride conflict)
#pragma unroll
  for (int jm = 0; jm < 3; ++jm) {
    int Mt = w + 4 * jm;
    int l0 = Mt * 16 + (lane >> 4) * 4;
#pragma unroll
    for (int nt = 0; nt < 4; ++nt) {
      int o = nt * 16 + (lane & 15);
      int lp = l0 ^ ((o & 7) << 2);
      *(f32x4*)(ol + o * 192 + lp) = acc[jm][nt];
    }
  }
  __syncthreads();

  // coalesced store to out[b][o][n][l]
  float* dst = out + (b * 64 * 128 + n) * 192;
#pragma unroll
  for (int j = 0; j < 12; ++j) {
    int f = j * 256 + t;
    int o = f / 48, g = f - o * 48;
    int lp = g * 4;
    int l = lp ^ ((o & 7) << 2);
    f32x4 v = *(const f32x4*)(ol + o * 192 + lp);
    *(f32x4*)(dst + o * (128 * 192) + l) = v;
  }
}

// ---------------------------------------------------------------------------
extern "C" void kernel_launch(void* const* d_in, const int* in_sizes, int n_in,
                              void* d_out, int out_size, void* d_ws, size_t ws_size,
                              hipStream_t stream) {
  const float* q  = (const float*)d_in[0];
  const float* wr = (const float*)d_in[1];
  const float* wi = (const float*)d_in[2];
  float* out = (float*)d_out;

  unsigned short* Xp = (unsigned short*)d_ws;            // 33.5 MB
  unsigned short* Yp = Xp + 16777216;                    // 33.5 MB

  hipFuncSetAttribute((const void*)k1_dft,  hipFuncAttributeMaxDynamicSharedMemorySize, 148480);
  hipFuncSetAttribute((const void*)k2_mix,  hipFuncAttributeMaxDynamicSharedMemorySize, 65536);
  hipFuncSetAttribute((const void*)k3_idft, hipFuncAttributeMaxDynamicSharedMemorySize, 57344);

  k1_dft<<<dim3(256), dim3(512), 148480, stream>>>(q, Xp);
  k2_mix<<<dim3(512), dim3(512), 65536, stream>>>(wr, wi, Xp, Yp);
  k3_idft<<<dim3(4096), dim3(256), 57344, stream>>>(Yp, out);
}

// Round 3
// 194.812 us; speedup vs baseline: 1.1453x; 1.1453x over previous
//
#include <hip/hip_runtime.h>
#include <stdint.h>

// FourierBlock: B=32, D=64, N=128, L=192, M=32 modes, LH=97.
// 4-kernel plan (all memory-bound, MFMA bf16 compute):
//   K1: q [B,D,N,L] -> X[b,n,i,cat] DFT, frag-packed bf16 in ws            (~235 MB)
//   K0: W fp32 [N,D,D,M] -> Wp bf16 frag-packed [n][m][c][nt][ic][lane][e] (~201 MB)
//   K2: per (n,m) streaming complex GEMM Y[b,o] = X·W, no LDS staging      (~134 MB, L3-warm)
//   K3: out = basis2 @ Y (iDFT), swizzled LDS transpose, coalesced stores  (~235 MB)
// ws: Xp 33.5MB @0, Yp 33.5MB @16777216 u16, Wp 67MB @33554432 u16 (total 134 MB).
// Round-3 fix: K2 epilogue store loop was j<4 (1024 items) but the tile is
// 512 short8's -> threads with f>=512 wrote garbage into other n's Yp rows.
// Correct bound is j<2.

typedef __attribute__((ext_vector_type(8))) short short8;
typedef __attribute__((ext_vector_type(4))) float f32x4;
typedef __attribute__((ext_vector_type(4))) unsigned short u16x4;

__device__ __forceinline__ unsigned short f2bf(float f) {
  union { float fv; uint32_t u; } v; v.fv = f;
  uint32_t u = v.u;
  u += 0x7fffu + ((u >> 16) & 1u);          // round-to-nearest-even
  return (unsigned short)(u >> 16);
}

__device__ __forceinline__ f32x4 zero4() { f32x4 z; z[0]=0.f; z[1]=0.f; z[2]=0.f; z[3]=0.f; return z; }

#define TWO_PI_OVER_L (6.283185307179586f / 192.0f)

// ---------------------------------------------------------------------------
// K1: DFT.  grid 256 = (n 128, ih 2), 512 thr (8 waves).  (unchanged, near-roofline)
// ---------------------------------------------------------------------------
__global__ __launch_bounds__(512, 2)
void k1_dft(const float* __restrict__ q, unsigned short* __restrict__ Xp) {
  extern __shared__ char smem[];
  const int t = threadIdx.x, lane = t & 63, w = t >> 6;
  const int n = blockIdx.x >> 1, ih = blockIdx.x & 1;

  unsigned short* qb = (unsigned short*)smem;
  char* Fb = smem + 65536;

  for (int idx = t; idx < 64 * 192; idx += 512) {
    int cat = idx / 192, l = idx - cat * 192;
    int m = cat >> 1;
    int r = (m * l) % 192;
    float ang = (float)r * TWO_PI_OVER_L;
    float v = (cat & 1) ? -__sinf(ang) : __cosf(ang);
    *(unsigned short*)(Fb + cat * 400 + l * 2) = f2bf(v);
  }

  f32x4 acc[8][4];
#pragma unroll
  for (int a = 0; a < 8; ++a)
#pragma unroll
    for (int bq = 0; bq < 4; ++bq) acc[a][bq] = zero4();

  for (int kc = 0; kc < 6; ++kc) {
#pragma unroll
    for (int j = 0; j < 16; ++j) {
      int f = j * 512 + t;
      int lg = f & 7, b = (f >> 3) & 31, il = f >> 8;
      const float4 v = *(const float4*)(q + (((b * 64 + ih * 32 + il) * 128 + n) * 192 + kc * 32 + lg * 4));
      u16x4 h; h[0] = f2bf(v.x); h[1] = f2bf(v.y); h[2] = f2bf(v.z); h[3] = f2bf(v.w);
      *(u16x4*)(qb + (il * 32 + b) * 32 + lg * 4) = h;
    }
    __syncthreads();

    short8 Bf[4];
#pragma unroll
    for (int nt = 0; nt < 4; ++nt) {
      int cat = nt * 16 + (lane & 15);
      Bf[nt] = *(const short8*)(Fb + cat * 400 + (kc * 32 + (lane >> 4) * 8) * 2);
    }
#pragma unroll
    for (int mt = 0; mt < 8; ++mt) {
      int Mt = w * 8 + mt;
      int il = Mt >> 1;
      int b = (Mt & 1) * 16 + (lane & 15);
      short8 A = *(const short8*)((const char*)qb + ((il * 32 + b) * 32 + (lane >> 4) * 8) * 2);
#pragma unroll
      for (int nt = 0; nt < 4; ++nt)
        acc[mt][nt] = __builtin_amdgcn_mfma_f32_16x16x32_bf16(A, Bf[nt], acc[mt][nt], 0, 0, 0);
    }
    __syncthreads();
  }

#pragma unroll
  for (int mt = 0; mt < 8; ++mt) {
    int Mt = w * 8 + mt;
    int il = Mt >> 1;
    int b0 = (Mt & 1) * 16 + (lane >> 4) * 4;
#pragma unroll
    for (int nt = 0; nt < 4; ++nt) {
      int cat = nt * 16 + (lane & 15);
      char* base = smem + cat * 2320 + il * 2;
      f32x4 v = acc[mt][nt];
#pragma unroll
      for (int r = 0; r < 4; ++r)
        *(unsigned short*)(base + (b0 + r) * 72) = f2bf(v[r]);
    }
  }
  __syncthreads();

  const int nbase = n * 131072;
#pragma unroll
  for (int j = 0; j < 16; ++j) {
    int f = j * 512 + t;
    int l2 = f & 63, Mt2 = (f >> 6) & 1, c = (f >> 7) & 1, m = f >> 8;
    int cat = 2 * m + c;
    int b = Mt2 * 16 + (l2 & 15);
    int i0 = (l2 >> 4) * 8;
    const char* base = smem + cat * 2320 + b * 72 + i0 * 2;
    u16x4 lo = *(const u16x4*)(base);
    u16x4 hi = *(const u16x4*)(base + 8);
    short8 vv;
    vv[0] = (short)lo[0]; vv[1] = (short)lo[1]; vv[2] = (short)lo[2]; vv[3] = (short)lo[3];
    vv[4] = (short)hi[0]; vv[5] = (short)hi[1]; vv[6] = (short)hi[2]; vv[7] = (short)hi[3];
    int off = nbase + ((((m * 2 + c) * 2 + ih) * 2 + Mt2) * 64 + l2) * 8;
    *(short8*)(Xp + off) = vv;
  }
}

// ---------------------------------------------------------------------------
// K0: W repack. grid 2048 = (n128, c2, nt4, ic2), 256 thr.
// Read W[n][i:ic*32+32][o:nt*16+16][m:32] fp32 coalesced -> LDS [i32][o16][m36pad]
// -> write bf16 frags Wp[n][m][c][nt][ic][lane64][e8]: e is i-dim (B-frag k-order).
// ---------------------------------------------------------------------------
__global__ __launch_bounds__(256, 4)
void k0_repack(const float* __restrict__ wr, const float* __restrict__ wi,
               unsigned short* __restrict__ Wp) {
  __shared__ unsigned short T[32 * 16 * 36];   // 36864 B
  const int t = threadIdx.x;
  const int bid = blockIdx.x;
  const int ic = bid & 1, nt = (bid >> 1) & 3, c = (bid >> 3) & 1, n = bid >> 4;
  const float* src = (c ? wi : wr) + ((n * 64 + ic * 32) * 64 + nt * 16) * 32;

#pragma unroll
  for (int j = 0; j < 16; ++j) {
    int f = j * 256 + t;                       // float4 units [0,4096)
    int mg = f & 7, o = (f >> 3) & 15, i = f >> 7;
    float4 v = *(const float4*)(src + i * 2048 + o * 32 + mg * 4);
    u16x4 h; h[0] = f2bf(v.x); h[1] = f2bf(v.y); h[2] = f2bf(v.z); h[3] = f2bf(v.w);
    *(u16x4*)(T + (i * 16 + o) * 36 + mg * 4) = h;
  }
  __syncthreads();

  unsigned short* dst = Wp + ((((n * 32) * 2 + c) * 4 + nt) * 2 + ic) * 512;
  // m stride in Wp = 8192 u16
#pragma unroll
  for (int j = 0; j < 8; ++j) {
    int f = j * 256 + t;                       // (m, lane-slot) [0,2048)
    int m = f >> 6, lidx = f & 63;
    int il0 = (lidx >> 4) * 8, ol = lidx & 15;
    short8 v;
#pragma unroll
    for (int e = 0; e < 8; ++e)
      v[e] = (short)T[((il0 + e) * 16 + ol) * 36 + m];
    *(short8*)(dst + m * 8192 + lidx * 8) = v;
  }
}

// ---------------------------------------------------------------------------
// K2: streaming complex mix. grid 4096 = (n128, m32), 256 thr (4 waves; wave w = o-chunk nt).
// All operands frag-packed in global: 12 coalesced short8 loads + 16 MFMA per wave.
// Epilogue: C-frags -> LDS [b32][132] -> 256B-coalesced Yp[n][b][cat][o] stores.
// ---------------------------------------------------------------------------
__global__ __launch_bounds__(256, 4)
void k2_mix(const unsigned short* __restrict__ Wp, const unsigned short* __restrict__ Xp,
            unsigned short* __restrict__ Yp) {
  __shared__ unsigned short Yl[32 * 132];      // row stride 132 u16 (conflict-free scatter)
  const int t = threadIdx.x, lane = t & 63, w = t >> 6;
  const int n = blockIdx.x >> 5, m = blockIdx.x & 31;

  // A-frags (X): Xp[n] + (((m*2+c)*2+ic)*2+Mt)*512 + lane*8
  const unsigned short* xb = Xp + n * 131072 + m * 4096 + lane * 8;
  short8 Ar[2][2], Ai[2][2];
#pragma unroll
  for (int ic = 0; ic < 2; ++ic)
#pragma unroll
    for (int Mt = 0; Mt < 2; ++Mt) {
      Ar[ic][Mt] = *(const short8*)(xb + (ic * 2 + Mt) * 512);
      Ai[ic][Mt] = *(const short8*)(xb + 2048 + (ic * 2 + Mt) * 512);
    }

  // B-frags (W): Wp + (n*32+m)*8192 + c*4096 + nt*1024 + ic*512 + lane*8
  const unsigned short* wb = Wp + (n * 32 + m) * 8192 + w * 1024 + lane * 8;
  short8 Br[2], Bi[2], nBi[2];
#pragma unroll
  for (int ic = 0; ic < 2; ++ic) {
    Br[ic] = *(const short8*)(wb + ic * 512);
    Bi[ic] = *(const short8*)(wb + 4096 + ic * 512);
#pragma unroll
    for (int e = 0; e < 8; ++e) nBi[ic][e] = Bi[ic][e] ^ (short)0x8000;   // -Wi
  }

  f32x4 acc[2][2];  // [cc][Mt]
#pragma unroll
  for (int a = 0; a < 2; ++a)
#pragma unroll
    for (int b2 = 0; b2 < 2; ++b2) acc[a][b2] = zero4();

#pragma unroll
  for (int ic = 0; ic < 2; ++ic)
#pragma unroll
    for (int Mt = 0; Mt < 2; ++Mt) {
      acc[0][Mt] = __builtin_amdgcn_mfma_f32_16x16x32_bf16(Ar[ic][Mt], Br[ic],  acc[0][Mt], 0, 0, 0);
      acc[0][Mt] = __builtin_amdgcn_mfma_f32_16x16x32_bf16(Ai[ic][Mt], nBi[ic], acc[0][Mt], 0, 0, 0);
      acc[1][Mt] = __builtin_amdgcn_mfma_f32_16x16x32_bf16(Ar[ic][Mt], Bi[ic],  acc[1][Mt], 0, 0, 0);
      acc[1][Mt] = __builtin_amdgcn_mfma_f32_16x16x32_bf16(Ai[ic][Mt], Br[ic],  acc[1][Mt], 0, 0, 0);
    }

  // C-frags -> LDS: Yl[b*132 + cc*64 + o]; banks (8g + ol/2) cover 32 -> 2-way max (free)
  const int ol = lane & 15, g = lane >> 4;
#pragma unroll
  for (int cc = 0; cc < 2; ++cc)
#pragma unroll
    for (int Mt = 0; Mt < 2; ++Mt) {
      f32x4 v = acc[cc][Mt];
#pragma unroll
      for (int r = 0; r < 4; ++r) {
        int b = Mt * 16 + g * 4 + r;
        Yl[b * 132 + cc * 64 + w * 16 + ol] = f2bf(v[r]);
      }
    }
  __syncthreads();

  // LDS -> Yp[n][b][2m+cc][o]: 16 lanes cover one b's 256B run -> full-line stores.
  // Tile = 32 b x 128 u16 = 512 short8's -> exactly 2 iterations of 256 threads.
  unsigned short* yb = Yp + n * 131072 + m * 128;
#pragma unroll
  for (int j = 0; j < 2; ++j) {
    int f = j * 256 + t;
    int b = f >> 4, rem = f & 15;
    const unsigned short* p = Yl + b * 132 + rem * 8;
    u16x4 lo = *(const u16x4*)(p);
    u16x4 hi = *(const u16x4*)(p + 4);
    short8 v;
    v[0] = (short)lo[0]; v[1] = (short)lo[1]; v[2] = (short)lo[2]; v[3] = (short)lo[3];
    v[4] = (short)hi[0]; v[5] = (short)hi[1]; v[6] = (short)hi[2]; v[7] = (short)hi[3];
    *(short8*)(yb + b * 4096 + rem * 8) = v;
  }
}

// ---------------------------------------------------------------------------
// K3: iDFT + transposed store. grid 4096 = (b 32, n 128), 256 thr.  (unchanged)
// ---------------------------------------------------------------------------
__global__ __launch_bounds__(256, 4)
void k3_idft(const unsigned short* __restrict__ Yp, float* __restrict__ out) {
  extern __shared__ char smem[];
  unsigned short* Yl = (unsigned short*)smem;
  float* ol = (float*)(smem + 8192);
  const int t = threadIdx.x, lane = t & 63, w = t >> 6;
  const int n = blockIdx.x & 127, b = blockIdx.x >> 7;

  const unsigned short* ysrc = Yp + (n * 32 + b) * 4096;
#pragma unroll
  for (int j = 0; j < 2; ++j) {
    int f = j * 256 + t;
    *(short8*)(Yl + f * 8) = *(const short8*)(ysrc + f * 8);
  }

  short8 Af[3][2];
#pragma unroll
  for (int jm = 0; jm < 3; ++jm) {
    int Mt = w + 4 * jm;
    int lt = Mt * 16 + (lane & 15);
#pragma unroll
    for (int kc = 0; kc < 2; ++kc) {
#pragma unroll
      for (int e = 0; e < 8; ++e) {
        int cat = kc * 32 + (lane >> 4) * 8 + e;
        int m = cat >> 1;
        int r = (m * lt) % 192;
        float ang = (float)r * TWO_PI_OVER_L;
        float coef = (m == 0) ? (1.0f / 192.0f) : (2.0f / 192.0f);
        float v = ((cat & 1) ? -__sinf(ang) : __cosf(ang)) * coef;
        Af[jm][kc][e] = (short)f2bf(v);
      }
    }
  }
  __syncthreads();

  f32x4 acc[3][4];
#pragma unroll
  for (int a = 0; a < 3; ++a)
#pragma unroll
    for (int bq = 0; bq < 4; ++bq) acc[a][bq] = zero4();

#pragma unroll
  for (int kc = 0; kc < 2; ++kc) {
    short8 Bf[4];
#pragma unroll
    for (int nt = 0; nt < 4; ++nt)
#pragma unroll
      for (int e = 0; e < 8; ++e) {
        int cat = kc * 32 + (lane >> 4) * 8 + e;
        Bf[nt][e] = (short)Yl[cat * 64 + nt * 16 + (lane & 15)];
      }
#pragma unroll
    for (int jm = 0; jm < 3; ++jm)
#pragma unroll
      for (int nt = 0; nt < 4; ++nt)
        acc[jm][nt] = __builtin_amdgcn_mfma_f32_16x16x32_bf16(Af[jm][kc], Bf[nt], acc[jm][nt], 0, 0, 0);
  }

#pragma unroll
  for (int jm = 0; jm < 3; ++jm) {
    int Mt = w + 4 * jm;
    int l0 = Mt * 16 + (lane >> 4) * 4;
#pragma unroll
    for (int nt = 0; nt < 4; ++nt) {
      int o = nt * 16 + (lane & 15);
      int lp = l0 ^ ((o & 7) << 2);
      *(f32x4*)(ol + o * 192 + lp) = acc[jm][nt];
    }
  }
  __syncthreads();

  float* dst = out + (b * 64 * 128 + n) * 192;
#pragma unroll
  for (int j = 0; j < 12; ++j) {
    int f = j * 256 + t;
    int o = f / 48, g = f - o * 48;
    int lp = g * 4;
    int l = lp ^ ((o & 7) << 2);
    f32x4 v = *(const f32x4*)(ol + o * 192 + lp);
    *(f32x4*)(dst + o * (128 * 192) + l) = v;
  }
}

// ---------------------------------------------------------------------------
extern "C" void kernel_launch(void* const* d_in, const int* in_sizes, int n_in,
                              void* d_out, int out_size, void* d_ws, size_t ws_size,
                              hipStream_t stream) {
  const float* q  = (const float*)d_in[0];
  const float* wr = (const float*)d_in[1];
  const float* wi = (const float*)d_in[2];
  float* out = (float*)d_out;

  unsigned short* Xp = (unsigned short*)d_ws;            // 33.5 MB
  unsigned short* Yp = Xp + 16777216;                    // 33.5 MB
  unsigned short* Wp = Xp + 33554432;                    // 67 MB

  hipFuncSetAttribute((const void*)k1_dft,  hipFuncAttributeMaxDynamicSharedMemorySize, 148480);
  hipFuncSetAttribute((const void*)k3_idft, hipFuncAttributeMaxDynamicSharedMemorySize, 57344);

  k1_dft<<<dim3(256), dim3(512), 148480, stream>>>(q, Xp);
  k0_repack<<<dim3(2048), dim3(256), 0, stream>>>(wr, wi, Wp);
  k2_mix<<<dim3(4096), dim3(256), 0, stream>>>(Wp, Xp, Yp);
  k3_idft<<<dim3(4096), dim3(256), 57344, stream>>>(Yp, out);
}

// Round 4
// 192.037 us; speedup vs baseline: 1.1618x; 1.0145x over previous
//
#include <hip/hip_runtime.h>
#include <stdint.h>

// FourierBlock: B=32, D=64, N=128, L=192, M=32 modes, LH=97.
// 3-kernel plan (all memory-bound, MFMA bf16 compute):
//   K1:  q [B,D,N,L] -> Xp[n][m][c][ih][Mt][lane][e] DFT, frag-packed bf16   (~235 MB)
//   K2f: fused W-repack + complex mix: per (n, o-quarter) block stages
//        W[n][:, o16, :] fp32 -> LDS (odd-stride transpose tile), computes
//        Y[b,o] = X·W complex per m via MFMA, stores Yp[n][b][cat][o] bf16   (~201 MB HBM)
//   K3:  out = basis2 @ Y (iDFT), swizzled LDS transpose, coalesced stores   (~235 MB)
// ws: Xp 33.5MB @0, Yp 33.5MB @16777216 u16. Requires ws >= 67 MiB.

typedef __attribute__((ext_vector_type(8))) short short8;
typedef __attribute__((ext_vector_type(4))) float f32x4;
typedef __attribute__((ext_vector_type(4))) unsigned short u16x4;

__device__ __forceinline__ unsigned short f2bf(float f) {
  union { float fv; uint32_t u; } v; v.fv = f;
  uint32_t u = v.u;
  u += 0x7fffu + ((u >> 16) & 1u);          // round-to-nearest-even
  return (unsigned short)(u >> 16);
}

__device__ __forceinline__ f32x4 zero4() { f32x4 z; z[0]=0.f; z[1]=0.f; z[2]=0.f; z[3]=0.f; return z; }

#define TWO_PI_OVER_L (6.283185307179586f / 192.0f)

// ---------------------------------------------------------------------------
// K1: DFT.  grid 256 = (n 128, ih 2), 512 thr (8 waves).  (unchanged)
// ---------------------------------------------------------------------------
__global__ __launch_bounds__(512, 2)
void k1_dft(const float* __restrict__ q, unsigned short* __restrict__ Xp) {
  extern __shared__ char smem[];
  const int t = threadIdx.x, lane = t & 63, w = t >> 6;
  const int n = blockIdx.x >> 1, ih = blockIdx.x & 1;

  unsigned short* qb = (unsigned short*)smem;
  char* Fb = smem + 65536;

  for (int idx = t; idx < 64 * 192; idx += 512) {
    int cat = idx / 192, l = idx - cat * 192;
    int m = cat >> 1;
    int r = (m * l) % 192;
    float ang = (float)r * TWO_PI_OVER_L;
    float v = (cat & 1) ? -__sinf(ang) : __cosf(ang);
    *(unsigned short*)(Fb + cat * 400 + l * 2) = f2bf(v);
  }

  f32x4 acc[8][4];
#pragma unroll
  for (int a = 0; a < 8; ++a)
#pragma unroll
    for (int bq = 0; bq < 4; ++bq) acc[a][bq] = zero4();

  for (int kc = 0; kc < 6; ++kc) {
#pragma unroll
    for (int j = 0; j < 16; ++j) {
      int f = j * 512 + t;
      int lg = f & 7, b = (f >> 3) & 31, il = f >> 8;
      const float4 v = *(const float4*)(q + (((b * 64 + ih * 32 + il) * 128 + n) * 192 + kc * 32 + lg * 4));
      u16x4 h; h[0] = f2bf(v.x); h[1] = f2bf(v.y); h[2] = f2bf(v.z); h[3] = f2bf(v.w);
      *(u16x4*)(qb + (il * 32 + b) * 32 + lg * 4) = h;
    }
    __syncthreads();

    short8 Bf[4];
#pragma unroll
    for (int nt = 0; nt < 4; ++nt) {
      int cat = nt * 16 + (lane & 15);
      Bf[nt] = *(const short8*)(Fb + cat * 400 + (kc * 32 + (lane >> 4) * 8) * 2);
    }
#pragma unroll
    for (int mt = 0; mt < 8; ++mt) {
      int Mt = w * 8 + mt;
      int il = Mt >> 1;
      int b = (Mt & 1) * 16 + (lane & 15);
      short8 A = *(const short8*)((const char*)qb + ((il * 32 + b) * 32 + (lane >> 4) * 8) * 2);
#pragma unroll
      for (int nt = 0; nt < 4; ++nt)
        acc[mt][nt] = __builtin_amdgcn_mfma_f32_16x16x32_bf16(A, Bf[nt], acc[mt][nt], 0, 0, 0);
    }
    __syncthreads();
  }

#pragma unroll
  for (int mt = 0; mt < 8; ++mt) {
    int Mt = w * 8 + mt;
    int il = Mt >> 1;
    int b0 = (Mt & 1) * 16 + (lane >> 4) * 4;
#pragma unroll
    for (int nt = 0; nt < 4; ++nt) {
      int cat = nt * 16 + (lane & 15);
      char* base = smem + cat * 2320 + il * 2;
      f32x4 v = acc[mt][nt];
#pragma unroll
      for (int r = 0; r < 4; ++r)
        *(unsigned short*)(base + (b0 + r) * 72) = f2bf(v[r]);
    }
  }
  __syncthreads();

  const int nbase = n * 131072;
#pragma unroll
  for (int j = 0; j < 16; ++j) {
    int f = j * 512 + t;
    int l2 = f & 63, Mt2 = (f >> 6) & 1, c = (f >> 7) & 1, m = f >> 8;
    int cat = 2 * m + c;
    int b = Mt2 * 16 + (l2 & 15);
    int i0 = (l2 >> 4) * 8;
    const char* base = smem + cat * 2320 + b * 72 + i0 * 2;
    u16x4 lo = *(const u16x4*)(base);
    u16x4 hi = *(const u16x4*)(base + 8);
    short8 vv;
    vv[0] = (short)lo[0]; vv[1] = (short)lo[1]; vv[2] = (short)lo[2]; vv[3] = (short)lo[3];
    vv[4] = (short)hi[0]; vv[5] = (short)hi[1]; vv[6] = (short)hi[2]; vv[7] = (short)hi[3];
    int off = nbase + ((((m * 2 + c) * 2 + ih) * 2 + Mt2) * 64 + l2) * 8;
    *(short8*)(Xp + off) = vv;
  }
}

// ---------------------------------------------------------------------------
// K2f: fused W-stage + complex mix. grid 512 = (n 128, oq 4), 512 thr (8 waves).
// LDS tile T[c2][i64][o16][m32]: o-stride 34 u16, i-stride 546 u16, c-stride
// 34944 u16 -> 139776 B. Odd strides spread the i<->m transpose gather banks.
// Wave w handles m in {4w..4w+3}, all 32 b, the block's 16 o's.
// ---------------------------------------------------------------------------
#define K2_OSTRIDE 34
#define K2_ISTRIDE 546        // 16*34 + 2
#define K2_CSTRIDE 34944      // 64*546
__global__ __launch_bounds__(512, 2)
void k2f_mix(const float* __restrict__ wr, const float* __restrict__ wi,
             const unsigned short* __restrict__ Xp, unsigned short* __restrict__ Yp) {
  extern __shared__ char smem[];
  unsigned short* T = (unsigned short*)smem;
  const int t = threadIdx.x, lane = t & 63, w = t >> 6;
  const int n = blockIdx.x >> 2, oq = blockIdx.x & 3;
  const int ol = lane & 15, il0 = (lane >> 4) * 8;

  // ---- stage W[n][i 0..63][oq*16 .. +16][m 0..32][c both] fp32 -> bf16 LDS
  // f decode: mg (float4-of-m) 8, o 16, i 64, c 2  -> 16384 float4, 32/thread
#pragma unroll
  for (int j = 0; j < 32; ++j) {
    int f = j * 512 + t;
    int mg = f & 7, o = (f >> 3) & 15, i = (f >> 7) & 63, c = (f >> 13) & 1;
    const float* src = (c ? wi : wr) + ((n * 64 + i) * 64 + oq * 16 + o) * 32 + mg * 4;
    float4 v = *(const float4*)src;
    u16x4 h; h[0] = f2bf(v.x); h[1] = f2bf(v.y); h[2] = f2bf(v.z); h[3] = f2bf(v.w);
    *(u16x4*)(T + c * K2_CSTRIDE + i * K2_ISTRIDE + o * K2_OSTRIDE + mg * 4) = h;
  }
  __syncthreads();

  // ---- per-m compute: A-frags streamed from Xp (coalesced 1KB), B gathered from LDS
#pragma unroll
  for (int mm = 0; mm < 4; ++mm) {
    int m = w * 4 + mm;
    f32x4 acc[2][2];  // [cc][Mt]
#pragma unroll
    for (int a = 0; a < 2; ++a)
#pragma unroll
      for (int b2 = 0; b2 < 2; ++b2) acc[a][b2] = zero4();

#pragma unroll
    for (int ic = 0; ic < 2; ++ic) {
      // A-frags: Xp[n][m][c][ic][Mt][lane][e]
      const unsigned short* xb = Xp + n * 131072 + m * 4096 + ic * 1024 + lane * 8;
      short8 Ar0 = *(const short8*)(xb);
      short8 Ar1 = *(const short8*)(xb + 512);
      short8 Ai0 = *(const short8*)(xb + 2048);
      short8 Ai1 = *(const short8*)(xb + 2048 + 512);

      // B-frags: T[c][ic*32 + il0 + e][ol][m]
      const unsigned short* tb = T + (ic * 32 + il0) * K2_ISTRIDE + ol * K2_OSTRIDE + m;
      short8 Br, Bi, nBi;
#pragma unroll
      for (int e = 0; e < 8; ++e) {
        Br[e] = (short)tb[e * K2_ISTRIDE];
        Bi[e] = (short)tb[K2_CSTRIDE + e * K2_ISTRIDE];
        nBi[e] = Bi[e] ^ (short)0x8000;   // -Wi
      }

      acc[0][0] = __builtin_amdgcn_mfma_f32_16x16x32_bf16(Ar0, Br,  acc[0][0], 0, 0, 0);
      acc[0][0] = __builtin_amdgcn_mfma_f32_16x16x32_bf16(Ai0, nBi, acc[0][0], 0, 0, 0);
      acc[0][1] = __builtin_amdgcn_mfma_f32_16x16x32_bf16(Ar1, Br,  acc[0][1], 0, 0, 0);
      acc[0][1] = __builtin_amdgcn_mfma_f32_16x16x32_bf16(Ai1, nBi, acc[0][1], 0, 0, 0);
      acc[1][0] = __builtin_amdgcn_mfma_f32_16x16x32_bf16(Ar0, Bi,  acc[1][0], 0, 0, 0);
      acc[1][0] = __builtin_amdgcn_mfma_f32_16x16x32_bf16(Ai0, Br,  acc[1][0], 0, 0, 0);
      acc[1][1] = __builtin_amdgcn_mfma_f32_16x16x32_bf16(Ar1, Bi,  acc[1][1], 0, 0, 0);
      acc[1][1] = __builtin_amdgcn_mfma_f32_16x16x32_bf16(Ai1, Br,  acc[1][1], 0, 0, 0);
    }

    // ---- epilogue: C-frag rows -> Yp[n][b][2m+cc][oq*16+ol]  (32B runs)
    const int g = lane >> 4;
#pragma unroll
    for (int cc = 0; cc < 2; ++cc) {
      int cat = 2 * m + cc;
#pragma unroll
      for (int Mt = 0; Mt < 2; ++Mt) {
        f32x4 v = acc[cc][Mt];
#pragma unroll
        for (int r = 0; r < 4; ++r) {
          int b = Mt * 16 + g * 4 + r;
          Yp[((n * 32 + b) * 64 + cat) * 64 + oq * 16 + ol] = f2bf(v[r]);
        }
      }
    }
  }
}

// ---------------------------------------------------------------------------
// K3: iDFT + transposed store. grid 4096 = (b 32, n 128), 256 thr.  (unchanged)
// ---------------------------------------------------------------------------
__global__ __launch_bounds__(256, 4)
void k3_idft(const unsigned short* __restrict__ Yp, float* __restrict__ out) {
  extern __shared__ char smem[];
  unsigned short* Yl = (unsigned short*)smem;
  float* ol = (float*)(smem + 8192);
  const int t = threadIdx.x, lane = t & 63, w = t >> 6;
  const int n = blockIdx.x & 127, b = blockIdx.x >> 7;

  const unsigned short* ysrc = Yp + (n * 32 + b) * 4096;
#pragma unroll
  for (int j = 0; j < 2; ++j) {
    int f = j * 256 + t;
    *(short8*)(Yl + f * 8) = *(const short8*)(ysrc + f * 8);
  }

  short8 Af[3][2];
#pragma unroll
  for (int jm = 0; jm < 3; ++jm) {
    int Mt = w + 4 * jm;
    int lt = Mt * 16 + (lane & 15);
#pragma unroll
    for (int kc = 0; kc < 2; ++kc) {
#pragma unroll
      for (int e = 0; e < 8; ++e) {
        int cat = kc * 32 + (lane >> 4) * 8 + e;
        int m = cat >> 1;
        int r = (m * lt) % 192;
        float ang = (float)r * TWO_PI_OVER_L;
        float coef = (m == 0) ? (1.0f / 192.0f) : (2.0f / 192.0f);
        float v = ((cat & 1) ? -__sinf(ang) : __cosf(ang)) * coef;
        Af[jm][kc][e] = (short)f2bf(v);
      }
    }
  }
  __syncthreads();

  f32x4 acc[3][4];
#pragma unroll
  for (int a = 0; a < 3; ++a)
#pragma unroll
    for (int bq = 0; bq < 4; ++bq) acc[a][bq] = zero4();

#pragma unroll
  for (int kc = 0; kc < 2; ++kc) {
    short8 Bf[4];
#pragma unroll
    for (int nt = 0; nt < 4; ++nt)
#pragma unroll
      for (int e = 0; e < 8; ++e) {
        int cat = kc * 32 + (lane >> 4) * 8 + e;
        Bf[nt][e] = (short)Yl[cat * 64 + nt * 16 + (lane & 15)];
      }
#pragma unroll
    for (int jm = 0; jm < 3; ++jm)
#pragma unroll
      for (int nt = 0; nt < 4; ++nt)
        acc[jm][nt] = __builtin_amdgcn_mfma_f32_16x16x32_bf16(Af[jm][kc], Bf[nt], acc[jm][nt], 0, 0, 0);
  }

#pragma unroll
  for (int jm = 0; jm < 3; ++jm) {
    int Mt = w + 4 * jm;
    int l0 = Mt * 16 + (lane >> 4) * 4;
#pragma unroll
    for (int nt = 0; nt < 4; ++nt) {
      int o = nt * 16 + (lane & 15);
      int lp = l0 ^ ((o & 7) << 2);
      *(f32x4*)(ol + o * 192 + lp) = acc[jm][nt];
    }
  }
  __syncthreads();

  float* dst = out + (b * 64 * 128 + n) * 192;
#pragma unroll
  for (int j = 0; j < 12; ++j) {
    int f = j * 256 + t;
    int o = f / 48, g = f - o * 48;
    int lp = g * 4;
    int l = lp ^ ((o & 7) << 2);
    f32x4 v = *(const f32x4*)(ol + o * 192 + lp);
    *(f32x4*)(dst + o * (128 * 192) + l) = v;
  }
}

// ---------------------------------------------------------------------------
extern "C" void kernel_launch(void* const* d_in, const int* in_sizes, int n_in,
                              void* d_out, int out_size, void* d_ws, size_t ws_size,
                              hipStream_t stream) {
  const float* q  = (const float*)d_in[0];
  const float* wr = (const float*)d_in[1];
  const float* wi = (const float*)d_in[2];
  float* out = (float*)d_out;

  unsigned short* Xp = (unsigned short*)d_ws;            // 33.5 MB
  unsigned short* Yp = Xp + 16777216;                    // 33.5 MB

  hipFuncSetAttribute((const void*)k1_dft,  hipFuncAttributeMaxDynamicSharedMemorySize, 148480);
  hipFuncSetAttribute((const void*)k2f_mix, hipFuncAttributeMaxDynamicSharedMemorySize, 139776);
  hipFuncSetAttribute((const void*)k3_idft, hipFuncAttributeMaxDynamicSharedMemorySize, 57344);

  k1_dft<<<dim3(256), dim3(512), 148480, stream>>>(q, Xp);
  k2f_mix<<<dim3(512), dim3(512), 139776, stream>>>(wr, wi, Xp, Yp);
  k3_idft<<<dim3(4096), dim3(256), 57344, stream>>>(Yp, out);
}